// Round 8
// baseline (1217.261 us; speedup 1.0000x reference)
//
#include <hip/hip_runtime.h>
#include <hip/hip_cooperative_groups.h>
#include <stdint.h>

namespace cg = cooperative_groups;

// ---------------------------------------------------------------------------
// GuidedSegmentTransformer  (B=2, S=512, DIN=256, D=256, H=8, NL=4)
// Round 8: cooperative mega-kernel (25.8 KB arena, occupancy-sized grid)
// with a deterministic multi-dispatch fallback if the coop launch is rejected.
// ---------------------------------------------------------------------------

typedef unsigned short u16;
typedef short  short8  __attribute__((ext_vector_type(8)));
typedef unsigned short ushort8 __attribute__((ext_vector_type(8)));
typedef unsigned int   u32x4   __attribute__((ext_vector_type(4)));
typedef float          f32x4   __attribute__((ext_vector_type(4)));

#define DEV static __device__ __forceinline__

DEV float b2f(u16 u){ union { unsigned int i; float f; } x; x.i = ((unsigned int)u) << 16; return x.f; }
DEV u16  f2b(float f){ union { float f; unsigned int i; } x; x.f = f;
                       unsigned int i = x.i; i += 0x7fffu + ((i >> 16) & 1u); return (u16)(i >> 16); }

DEV float blockSum(float v, float* red, int t){
  #pragma unroll
  for (int m = 32; m; m >>= 1) v += __shfl_xor(v, m, 64);
  __syncthreads();
  if ((t & 63) == 0) red[t >> 6] = v;
  __syncthreads();
  float s = red[0] + red[1] + red[2] + red[3];
  return s;
}

struct MP {
  const float *xF, *b_in, *pos, *bq, *bk, *bv, *bo, *lng, *lnb;
  const float *c1w, *c1b, *c2w, *c2b;
  const float *h1w, *h1b, *g1, *be1, *h2w, *h2b, *g2, *be2, *h3w, *h3b;
  const float *srcX, *srcWin, *srcWq, *srcWk, *srcWv, *srcWo;
  float *x1f, *x2sum, *hcat, *sn; int* ctr;
  u16 *x1b, *qkv, *attb, *pwb, *W2r, *cvt;
  const u16 *xc, *Winc, *Wqc, *Wkc, *Wvc, *Woc;
  float* out;
};

#define ARENA 26368

// ---------------------------------------------------------------------------
// front body: convert (1.37M elems) + sn + W2r + x2sum/hcat/ctr zero
// ---------------------------------------------------------------------------
DEV void front_body(const MP& p, int bid, int t, int G, char* smem){
  long long stride = (long long)G * 256;
  for (long long e = (long long)bid*256 + t; e < 1376256; e += stride){
    const float* s; long long off;
    if (e < 262144){ s = p.srcX;  off = 0; }
    else if (e <  327680){ s = p.srcWin; off = 262144; }
    else if (e <  589824){ s = p.srcWq;  off = 327680; }
    else if (e <  851968){ s = p.srcWk;  off = 589824; }
    else if (e < 1114112){ s = p.srcWv;  off = 851968; }
    else                 { s = p.srcWo;  off = 1114112; }
    p.cvt[e] = f2b(s[e - off]);
  }
  float* red = (float*)smem;
  for (int row = bid; row < 1024; row += G){
    float v = p.xF[row*256 + t];
    float s = blockSum(v*v, red, t);
    if (t == 0) p.sn[row] = s;
    __syncthreads();
  }
  for (int e = bid*256 + t; e < 98304; e += G*256){
    int co = e / 384, kk = e - co*384;
    int k = kk >> 7, ci = kk & 127;
    p.W2r[e] = f2b(p.c2w[co*384 + ci*3 + k]);
  }
  for (int i = bid*256 + t; i < 262144; i += G*256) p.x2sum[i] = 0.f;
  if (bid == 0){
    for (int i = t; i < 1024; i += 256) p.hcat[i] = 0.f;
    if (t == 0) *p.ctr = 0;
  }
}

// ---------------------------------------------------------------------------
// 64x64x256 NT GEMM core. arena use: 10240 B
// ---------------------------------------------------------------------------
DEV void gemm64_core(const u16* __restrict__ A, const u16* __restrict__ Bp,
                     int m0, int n0, int t, char* smem, f32x4 acc[4]){
  u16* As = (u16*)smem;            // 64*40
  u16* Bs = (u16*)(smem + 5120);   // 64*40
  int w = t >> 6, lane = t & 63, l15 = lane & 15, quad = lane >> 4;
  for (int k0 = 0; k0 < 256; k0 += 32){
    { int row = t >> 2, c = (t & 3)*8;
      *(u32x4*)&As[row*40 + c] = *(const u32x4*)&A[(m0+row)*256 + k0 + c]; }
    { int krow = t >> 3, nc = t & 7;
      ushort8 v = *(const ushort8*)&Bp[(k0+krow)*256 + n0 + nc*8];
      #pragma unroll
      for (int i = 0; i < 8; i++) Bs[(nc*8 + i)*40 + krow] = v[i]; }
    __syncthreads();
    short8 a = *(const short8*)&As[(w*16 + l15)*40 + quad*8];
    #pragma unroll
    for (int ni = 0; ni < 4; ni++){
      short8 b8 = *(const short8*)&Bs[(ni*16 + l15)*40 + quad*8];
      acc[ni] = __builtin_amdgcn_mfma_f32_16x16x32_bf16(a, b8, acc[ni], 0, 0, 0);
    }
    __syncthreads();
  }
}

// ---------------------------------------------------------------------------
// conv body: unit u in [0,8192): n = u>>3, coHalf = u&1, lq = (u>>1)&3.
// Covers 128 co x 128 l (2 chunks). arena: r1t 17952 + pwAll 528 = 18480 B.
// ---------------------------------------------------------------------------
DEV void conv_body(const MP& p, int u, int t, char* smem){
  u16*   r1t   = (u16*)smem;
  float* pwAll = (float*)(smem + 17952);     // 132 floats
  int w = t >> 6, lane = t & 63, l15 = lane & 15, quad = lane >> 4;
  int n = u >> 3, sub = u & 7, co0 = (sub & 1)*128, lq = sub >> 1;
  int lbase = lq*128;

  for (int i = t; i < 132; i += 256){
    int l = lbase - 2 + i;
    pwAll[i] = ((unsigned)l < 512u) ? b2f(p.pwb[n*512 + l]) : 0.f;
  }
  int ci = t & 127, half = t >> 7;
  float w0 = p.c1w[ci*3], w1 = p.c1w[ci*3+1], w2 = p.c1w[ci*3+2], cb = p.c1b[ci];

  short8 aF[12][2];
  #pragma unroll
  for (int s = 0; s < 12; s++)
    #pragma unroll
    for (int mi = 0; mi < 2; mi++)
      aF[s][mi] = *(const short8*)&p.W2r[(co0 + w*32 + mi*16 + l15)*384 + s*32 + quad*8];

  float bias[2][4], accsum[2][4] = {};
  #pragma unroll
  for (int mi = 0; mi < 2; mi++)
    #pragma unroll
    for (int r = 0; r < 4; r++) bias[mi][r] = p.c2b[co0 + w*32 + mi*16 + quad*4 + r];

  for (int cc = 0; cc < 2; cc++){
    int l0 = lbase + cc*64;
    __syncthreads();                         // pwAll ready / prev r1t reads done
    #pragma unroll
    for (int j = 0; j < 33; j++){
      int g = half + 2*j;                    // half0: 0..64, half1: 1..65
      int lidx = l0 - 1 + g;
      int li = cc*64 + g;                    // pwAll index of lidx-1
      float v = fmaxf(w0*pwAll[li] + w1*pwAll[li+1] + w2*pwAll[li+2] + cb, 0.f);
      v = ((unsigned)lidx < 512u) ? v : 0.f;
      r1t[g*136 + ci] = f2b(v);
    }
    __syncthreads();
    f32x4 acc[2][4] = {};
    #pragma unroll
    for (int s = 0; s < 12; s++){
      int kq = s >> 2, ci0 = (s & 3)*32;
      #pragma unroll
      for (int nj = 0; nj < 4; nj++){
        short8 b8 = *(const short8*)&r1t[(nj*16 + l15 + kq)*136 + ci0 + quad*8];
        acc[0][nj] = __builtin_amdgcn_mfma_f32_16x16x32_bf16(aF[s][0], b8, acc[0][nj], 0, 0, 0);
        acc[1][nj] = __builtin_amdgcn_mfma_f32_16x16x32_bf16(aF[s][1], b8, acc[1][nj], 0, 0, 0);
      }
    }
    #pragma unroll
    for (int mi = 0; mi < 2; mi++)
      #pragma unroll
      for (int r = 0; r < 4; r++){
        float s4 = 0.f;
        #pragma unroll
        for (int nj = 0; nj < 4; nj++) s4 += fmaxf(acc[mi][nj][r] + bias[mi][r], 0.f);
        accsum[mi][r] += s4;
      }
  }
  #pragma unroll
  for (int mi = 0; mi < 2; mi++)
    #pragma unroll
    for (int r = 0; r < 4; r++){
      float s = accsum[mi][r];
      s += __shfl_xor(s, 1, 64); s += __shfl_xor(s, 2, 64);
      s += __shfl_xor(s, 4, 64); s += __shfl_xor(s, 8, 64);
      if (l15 == 0)
        atomicAdd(&p.x2sum[n*256 + co0 + w*32 + mi*16 + quad*4 + r], s * (1.f/512.f));
    }
}

DEV void conv_grab(const MP& p, int t, char* smem, int* slotS, int maxU){
  for (int it = 0; it < maxU; it++){
    if (t == 0) *slotS = atomicAdd(p.ctr, 1);
    __syncthreads();
    int u = *slotS;
    __syncthreads();
    if (u >= 8192) break;
    conv_body(p, u, t, smem);
  }
}

// ---------------------------------------------------------------------------
// pw body (unit [0,128)). arena 10240 B
// ---------------------------------------------------------------------------
DEV void pw_body(const MP& p, int u, int t, char* smem){
  u16* As = (u16*)smem;
  u16* Bs = (u16*)(smem + 5120);
  int w = t >> 6, lane = t & 63, l15 = lane & 15, quad = lane >> 4;
  int m0 = (u & 7)*64, n0 = ((u >> 3) & 7)*64, z = u >> 6;
  const u16* A = p.xc + z*131072;
  const float* snp = p.sn + z*512;
  u16* Cb = p.pwb + z*262144;

  f32x4 acc[4] = {};
  for (int k0 = 0; k0 < 256; k0 += 32){
    { int row = t >> 2, c = (t & 3)*8;
      *(u32x4*)&As[row*40 + c] = *(const u32x4*)&A[(m0+row)*256 + k0 + c];
      *(u32x4*)&Bs[row*40 + c] = *(const u32x4*)&A[(n0+row)*256 + k0 + c]; }
    __syncthreads();
    short8 a = *(const short8*)&As[(w*16 + l15)*40 + quad*8];
    #pragma unroll
    for (int ni = 0; ni < 4; ni++){
      short8 b8 = *(const short8*)&Bs[(ni*16 + l15)*40 + quad*8];
      acc[ni] = __builtin_amdgcn_mfma_f32_16x16x32_bf16(a, b8, acc[ni], 0, 0, 0);
    }
    __syncthreads();
  }
  #pragma unroll
  for (int ni = 0; ni < 4; ni++)
    #pragma unroll
    for (int r = 0; r < 4; r++){
      int row = m0 + w*16 + quad*4 + r, col = n0 + ni*16 + l15;
      float dist = fmaxf(snp[row] + snp[col] - 2.f*acc[ni][r], 0.f);
      Cb[row*512 + col] = f2b(__expf(-dist * (1.f/256.f)));
    }
}

DEV void embed_body(const MP& p, int u, int t, char* smem){
  int m0 = (u & 15)*64, n0 = (u >> 4)*64;
  int w = t >> 6, lane = t & 63, l15 = lane & 15, quad = lane >> 4;
  f32x4 acc[4] = {};
  gemm64_core(p.xc, p.Winc, m0, n0, t, smem, acc);
  #pragma unroll
  for (int ni = 0; ni < 4; ni++)
    #pragma unroll
    for (int r = 0; r < 4; r++){
      int row = m0 + w*16 + quad*4 + r, col = n0 + ni*16 + l15;
      float v = acc[ni][r] + p.b_in[col] + p.pos[(row & 511)*256 + col];
      p.x1f[row*256 + col] = v; p.x1b[row*256 + col] = f2b(v);
    }
}

DEV void qkv_body(const MP& p, int L, int u, int t, char* smem){
  int m0 = (u & 15)*64, n0 = ((u >> 4) & 3)*64, z = u >> 6;
  const u16* W = (z == 0) ? (p.Wqc + L*65536) : ((z == 1) ? (p.Wkc + L*65536) : (p.Wvc + L*65536));
  const float* bias = (z == 0) ? (p.bq + L*256) : ((z == 1) ? (p.bk + L*256) : (p.bv + L*256));
  u16* out = p.qkv + z*262144;
  int w = t >> 6, lane = t & 63, l15 = lane & 15, quad = lane >> 4;
  f32x4 acc[4] = {};
  gemm64_core(p.x1b, W, m0, n0, t, smem, acc);
  #pragma unroll
  for (int ni = 0; ni < 4; ni++)
    #pragma unroll
    for (int r = 0; r < 4; r++){
      int row = m0 + w*16 + quad*4 + r, col = n0 + ni*16 + l15;
      out[row*256 + col] = f2b(acc[ni][r] + bias[col]);
    }
}

// ---------------------------------------------------------------------------
// attn body, K chunked (128 keys). arena use max 26112 B.
// ---------------------------------------------------------------------------
DEV void attn_body(const MP& p, int u, int t, char* smem){
  const u16* Qb = p.qkv;
  const u16* Kb = p.qkv + 262144;
  const u16* Vb = p.qkv + 524288;
  u16* Qs = (u16*)smem;              // 64*32   (QK phase)
  u16* Kc = (u16*)(smem + 4096);     // 128*32  (QK phase)
  u16* Ps = (u16*)smem;              // 64*136  (PV phase, aliases Qs/Kc)
  u16* Vt = (u16*)(smem + 17408);    // 32*136  (PV phase)
  int w = t >> 6, lane = t & 63, l15 = lane & 15, quad = lane >> 4;
  int qt = u & 7, h = (u >> 3) & 7, b = u >> 6;
  int row0 = b*512, colh = h*32;

  { int row = t >> 2, c = (t & 3)*8;
    *(u32x4*)&Qs[row*32 + c] = *(const u32x4*)&Qb[(row0 + qt*64 + row)*256 + colh + c]; }
  __syncthreads();
  short8 aq = *(const short8*)&Qs[(w*16 + l15)*32 + quad*8];

  const f32x4 z4 = {0.f, 0.f, 0.f, 0.f};
  f32x4 sc[32];
  for (int cch = 0; cch < 4; cch++){
    __syncthreads();                 // prev chunk's Kc reads done (and aq read on cch=0)
    #pragma unroll
    for (int i = 0; i < 2; i++){
      int ci = i*256 + t; int row = ci >> 2, c = (ci & 3)*8;
      *(u32x4*)&Kc[row*32 + c] = *(const u32x4*)&Kb[(row0 + cch*128 + row)*256 + colh + c];
    }
    __syncthreads();
    #pragma unroll
    for (int k2 = 0; k2 < 8; k2++){
      short8 bk8 = *(const short8*)&Kc[(k2*16 + l15)*32 + quad*8];
      sc[cch*8 + k2] = __builtin_amdgcn_mfma_f32_16x16x32_bf16(aq, bk8, z4, 0, 0, 0);
    }
  }
  float mx[4] = {-1e30f, -1e30f, -1e30f, -1e30f};
  #pragma unroll
  for (int kt = 0; kt < 32; kt++)
    #pragma unroll
    for (int r = 0; r < 4; r++) mx[r] = fmaxf(mx[r], sc[kt][r]);
  #pragma unroll
  for (int r = 0; r < 4; r++){
    mx[r] = fmaxf(mx[r], __shfl_xor(mx[r], 1, 64));
    mx[r] = fmaxf(mx[r], __shfl_xor(mx[r], 2, 64));
    mx[r] = fmaxf(mx[r], __shfl_xor(mx[r], 4, 64));
    mx[r] = fmaxf(mx[r], __shfl_xor(mx[r], 8, 64));
  }
  float sm[4] = {0.f, 0.f, 0.f, 0.f};
  const float is = 1.f/16.f;                  // scale = sqrt(D)=16
  #pragma unroll
  for (int kt = 0; kt < 32; kt++)
    #pragma unroll
    for (int r = 0; r < 4; r++){
      float pr = __expf(fminf((sc[kt][r] - mx[r]) * is, 0.f));
      sc[kt][r] = pr; sm[r] += pr;
    }
  #pragma unroll
  for (int r = 0; r < 4; r++){
    sm[r] += __shfl_xor(sm[r], 1, 64); sm[r] += __shfl_xor(sm[r], 2, 64);
    sm[r] += __shfl_xor(sm[r], 4, 64); sm[r] += __shfl_xor(sm[r], 8, 64);
  }
  float inv[4];
  #pragma unroll
  for (int r = 0; r < 4; r++) inv[r] = 1.f / sm[r];

  f32x4 o[2] = {};
  for (int cch = 0; cch < 4; cch++){
    __syncthreads();                 // prev chunk's Ps/Vt reads done (Kc reads on cch=0)
    #pragma unroll
    for (int kk = 0; kk < 8; kk++){
      int kt = cch*8 + kk;
      #pragma unroll
      for (int r = 0; r < 4; r++)
        Ps[(w*16 + quad*4 + r)*136 + kk*16 + l15] = f2b(sc[kt][r] * inv[r]);
    }
    #pragma unroll
    for (int i = 0; i < 2; i++){
      int ci = i*256 + t; int key = ci >> 2; int c = (ci & 3)*8;
      ushort8 v = *(const ushort8*)&Vb[(row0 + cch*128 + key)*256 + colh + c];
      #pragma unroll
      for (int j = 0; j < 8; j++) Vt[(c + j)*136 + key] = v[j];
    }
    __syncthreads();
    #pragma unroll
    for (int ks = 0; ks < 4; ks++){
      short8 ap = *(const short8*)&Ps[(w*16 + l15)*136 + ks*32 + quad*8];
      #pragma unroll
      for (int ni = 0; ni < 2; ni++){
        short8 bv = *(const short8*)&Vt[(ni*16 + l15)*136 + ks*32 + quad*8];
        o[ni] = __builtin_amdgcn_mfma_f32_16x16x32_bf16(ap, bv, o[ni], 0, 0, 0);
      }
    }
  }
  #pragma unroll
  for (int ni = 0; ni < 2; ni++)
    #pragma unroll
    for (int r = 0; r < 4; r++)
      p.attb[(row0 + qt*64 + w*16 + quad*4 + r)*256 + colh + ni*16 + l15] = f2b(o[ni][r]);
}

// ---------------------------------------------------------------------------
// projln body (unit [0,16)). arena use 25600 B.
// ---------------------------------------------------------------------------
DEV void projln_body(const MP& p, int L, int u, int t, char* smem){
  const u16* Wo = p.Woc + L*65536;
  const float* bo = p.bo + L*256;
  const float* lng = p.lng + L*256;
  const float* lnb = p.lnb + L*256;
  u16* As = (u16*)smem;             // 64*40
  u16* Bs = (u16*)(smem + 5120);    // 256*40
  int w = t >> 6, lane = t & 63, l15 = lane & 15, quad = lane >> 4;
  int m0 = u*64;

  f32x4 acc[16] = {};
  for (int k0 = 0; k0 < 256; k0 += 32){
    { int row = t >> 2, c = (t & 3)*8;
      *(u32x4*)&As[row*40 + c] = *(const u32x4*)&p.attb[(m0+row)*256 + k0 + c]; }
    #pragma unroll
    for (int it = 0; it < 4; it++){
      int krow = (t >> 5) + it*8, nc = t & 31;
      ushort8 v = *(const ushort8*)&Wo[(k0+krow)*256 + nc*8];
      #pragma unroll
      for (int i = 0; i < 8; i++) Bs[(nc*8 + i)*40 + krow] = v[i];
    }
    __syncthreads();
    short8 a = *(const short8*)&As[(w*16 + l15)*40 + quad*8];
    #pragma unroll
    for (int nj = 0; nj < 16; nj++){
      short8 b8 = *(const short8*)&Bs[(nj*16 + l15)*40 + quad*8];
      acc[nj] = __builtin_amdgcn_mfma_f32_16x16x32_bf16(a, b8, acc[nj], 0, 0, 0);
    }
    __syncthreads();
  }
  #pragma unroll
  for (int r = 0; r < 4; r++){
    int row = m0 + w*16 + quad*4 + r;
    float vv[16]; float s1 = 0.f;
    #pragma unroll
    for (int nj = 0; nj < 16; nj++){
      int col = nj*16 + l15;
      float v = acc[nj][r] + bo[col] + p.x1f[row*256 + col];
      vv[nj] = v; s1 += v;
    }
    s1 += __shfl_xor(s1, 1, 64); s1 += __shfl_xor(s1, 2, 64);
    s1 += __shfl_xor(s1, 4, 64); s1 += __shfl_xor(s1, 8, 64);
    float mean = s1 * (1.f/256.f);
    float s2 = 0.f;
    #pragma unroll
    for (int nj = 0; nj < 16; nj++){ float d = vv[nj] - mean; s2 += d*d; }
    s2 += __shfl_xor(s2, 1, 64); s2 += __shfl_xor(s2, 2, 64);
    s2 += __shfl_xor(s2, 4, 64); s2 += __shfl_xor(s2, 8, 64);
    float rs = rsqrtf(s2 * (1.f/256.f) + 1e-5f);
    #pragma unroll
    for (int nj = 0; nj < 16; nj++){
      int col = nj*16 + l15;
      float y = (vv[nj] - mean) * rs * lng[col] + lnb[col];
      p.x1f[row*256 + col] = y;
      p.x1b[row*256 + col] = f2b(y);
    }
  }
}

DEV void pool_body(const MP& p, int u, int t){
  int sc = u & 7, b = u >> 3;
  float a1 = 0.f, a2 = 0.f;
  for (int i = 0; i < 64; i++){
    int s = sc*64 + i; int n = b*512 + s;
    a1 += p.x1f[n*256 + t];
    a2 += p.x2sum[n*256 + t] + p.pos[s*256 + t];
  }
  atomicAdd(&p.hcat[b*512 + t], a1);
  atomicAdd(&p.hcat[b*512 + 256 + t], a2);
}

DEV void mlp_body(const MP& p, int b, int t, char* smem){
  float* hv  = (float*)smem;           // 512
  float* z1  = (float*)(smem + 2048);  // 256
  float* z2  = (float*)(smem + 3072);  // 128
  float* red = (float*)(smem + 3584);  // 4
  hv[t]       = p.hcat[b*512 + t]       * (1.f/512.f);
  hv[t + 256] = p.hcat[b*512 + 256 + t] * (1.f/512.f);
  __syncthreads();
  float a = p.h1b[t];
  for (int k = 0; k < 512; k++) a += hv[k] * p.h1w[k*256 + t];
  float mean = blockSum(a, red, t) * (1.f/256.f);
  float d = a - mean;
  float var = blockSum(d*d, red, t) * (1.f/256.f);
  float y = d * rsqrtf(var + 1e-5f) * p.g1[t] + p.be1[t];
  z1[t] = fmaxf(y, 0.f);
  __syncthreads();
  float a2 = 0.f;
  if (t < 128){ a2 = p.h2b[t]; for (int k = 0; k < 256; k++) a2 += z1[k] * p.h2w[k*128 + t]; }
  float mean2 = blockSum(t < 128 ? a2 : 0.f, red, t) * (1.f/128.f);
  float d2 = a2 - mean2;
  float var2 = blockSum(t < 128 ? d2*d2 : 0.f, red, t) * (1.f/128.f);
  if (t < 128) z2[t] = fmaxf(d2 * rsqrtf(var2 + 1e-5f) * p.g2[t] + p.be2[t], 0.f);
  __syncthreads();
  float pr = (t < 128) ? z2[t] * p.h3w[t] : 0.f;
  float s = blockSum(pr, red, t);
  if (t == 0) p.out[b] = s + p.h3b[0];
}

// ---------------------------------------------------------------------------
// mega kernel (cooperative)
// ---------------------------------------------------------------------------
__global__ __launch_bounds__(256, 2) void mega(MP p){
  __shared__ __align__(16) char smem[ARENA];
  __shared__ int slotS;
  cg::grid_group grid = cg::this_grid();
  int bid = blockIdx.x, t = threadIdx.x, G = gridDim.x;

  front_body(p, bid, t, G, smem);
  grid.sync();

  if (bid < 64) embed_body(p, bid, t, smem);
  else if (bid < 192) pw_body(p, bid - 64, t, smem);
  grid.sync();

  for (int L = 0; L < 4; L++){
    if (bid < 192) qkv_body(p, L, bid, t, smem); else conv_grab(p, t, smem, &slotS, 2);
    grid.sync();
    if (bid < 128) attn_body(p, bid, t, smem);   else conv_grab(p, t, smem, &slotS, 2);
    grid.sync();
    if (bid < 16) projln_body(p, L, bid, t, smem); else conv_grab(p, t, smem, &slotS, 2);
    grid.sync();
  }
  conv_grab(p, t, smem, &slotS, 1000000);   // drain remaining units
  grid.sync();
  if (bid < 16) pool_body(p, bid, t);
  grid.sync();
  if (bid < 2) mlp_body(p, bid, t, smem);
}

// ---------------------------------------------------------------------------
// fallback wrappers (identical bodies, ordinary dispatches)
// ---------------------------------------------------------------------------
__global__ __launch_bounds__(256) void kF_front(MP p){
  __shared__ __align__(16) char smem[ARENA];
  front_body(p, blockIdx.x, threadIdx.x, gridDim.x, smem);
}
__global__ __launch_bounds__(256) void kF_embedpw(MP p){
  __shared__ __align__(16) char smem[ARENA];
  int bx = blockIdx.x;
  if (bx < 64) embed_body(p, bx, threadIdx.x, smem);
  else pw_body(p, bx - 64, threadIdx.x, smem);
}
__global__ __launch_bounds__(256) void kF_conv(MP p){
  __shared__ __align__(16) char smem[ARENA];
  conv_body(p, blockIdx.x, threadIdx.x, smem);
}
__global__ __launch_bounds__(256) void kF_qkv(MP p, int L){
  __shared__ __align__(16) char smem[ARENA];
  qkv_body(p, L, blockIdx.x, threadIdx.x, smem);
}
__global__ __launch_bounds__(256) void kF_attn(MP p){
  __shared__ __align__(16) char smem[ARENA];
  attn_body(p, blockIdx.x, threadIdx.x, smem);
}
__global__ __launch_bounds__(256) void kF_projln(MP p, int L){
  __shared__ __align__(16) char smem[ARENA];
  projln_body(p, L, blockIdx.x, threadIdx.x, smem);
}
__global__ __launch_bounds__(256) void kF_pool(MP p){
  pool_body(p, blockIdx.x, threadIdx.x);
}
__global__ __launch_bounds__(256) void kF_mlp(MP p){
  __shared__ __align__(16) char smem[ARENA];
  mlp_body(p, blockIdx.x, threadIdx.x, smem);
}

// ---------------------------------------------------------------------------
extern "C" void kernel_launch(void* const* d_in, const int* in_sizes, int n_in,
                              void* d_out, int out_size, void* d_ws, size_t ws_size,
                              hipStream_t stream){
  (void)in_sizes; (void)n_in; (void)out_size; (void)ws_size;
  char* ws = (char*)d_ws;
  MP P;
  P.xF   = (const float*)d_in[0];
  P.b_in = (const float*)d_in[3];
  P.pos  = (const float*)d_in[4];
  P.bq   = (const float*)d_in[9];
  P.bk   = (const float*)d_in[10];
  P.bv   = (const float*)d_in[11];
  P.bo   = (const float*)d_in[12];
  P.lng  = (const float*)d_in[13];
  P.lnb  = (const float*)d_in[14];
  P.c1w  = (const float*)d_in[15];
  P.c1b  = (const float*)d_in[16];
  P.c2w  = (const float*)d_in[17];
  P.c2b  = (const float*)d_in[18];
  P.h1w  = (const float*)d_in[19];
  P.h1b  = (const float*)d_in[20];
  P.g1   = (const float*)d_in[21];
  P.be1  = (const float*)d_in[22];
  P.h2w  = (const float*)d_in[23];
  P.h2b  = (const float*)d_in[24];
  P.g2   = (const float*)d_in[25];
  P.be2  = (const float*)d_in[26];
  P.h3w  = (const float*)d_in[27];
  P.h3b  = (const float*)d_in[28];
  P.srcX  = (const float*)d_in[0];
  P.srcWin= (const float*)d_in[2];
  P.srcWq = (const float*)d_in[5];
  P.srcWk = (const float*)d_in[6];
  P.srcWv = (const float*)d_in[7];
  P.srcWo = (const float*)d_in[8];

  P.x1f   = (float*)(ws + 0);
  P.x2sum = (float*)(ws + 2097152);
  P.hcat  = (float*)(ws + 3145728);
  P.sn    = (float*)(ws + 3149824);
  P.ctr   = (int*)  (ws + 3153920);
  P.x1b   = (u16*)  (ws + 3158016);
  P.qkv   = (u16*)  (ws + 3682304);
  P.attb  = (u16*)  (ws + 5255168);
  P.pwb   = (u16*)  (ws + 5779456);
  P.W2r   = (u16*)  (ws + 6828032);
  P.cvt   = (u16*)  (ws + 8388608);
  P.xc    = P.cvt;
  P.Winc  = P.cvt + 262144;
  P.Wqc   = P.cvt + 327680;
  P.Wkc   = P.cvt + 589824;
  P.Wvc   = P.cvt + 851968;
  P.Woc   = P.cvt + 1114112;
  P.out   = (float*)d_out;

  bool coop = false;
  int occ = 0;
  if (hipOccupancyMaxActiveBlocksPerMultiprocessor(&occ, (const void*)mega, 256, 0) == hipSuccess
      && occ >= 1){
    int grid = occ * 256; if (grid > 512) grid = 512;
    if (grid >= 256){
      void* args[] = { &P };
      coop = (hipLaunchCooperativeKernel((const void*)mega, dim3(grid), dim3(256),
                                         args, 0, stream) == hipSuccess);
    }
  }
  if (!coop){
    kF_front  <<<512, 256, 0, stream>>>(P);
    kF_embedpw<<<192, 256, 0, stream>>>(P);
    kF_conv   <<<8192, 256, 0, stream>>>(P);
    for (int L = 0; L < 4; L++){
      kF_qkv   <<<192, 256, 0, stream>>>(P, L);
      kF_attn  <<<128, 256, 0, stream>>>(P);
      kF_projln<<<16, 256, 0, stream>>>(P, L);
    }
    kF_pool<<<16, 256, 0, stream>>>(P);
    kF_mlp <<<2, 256, 0, stream>>>(P);
  }
}

// Round 9
// 608.492 us; speedup vs baseline: 2.0005x; 2.0005x over previous
//
#include <hip/hip_runtime.h>
#include <stdint.h>

// ---------------------------------------------------------------------------
// GuidedSegmentTransformer  (B=2, S=512, DIN=256, D=256, H=8, NL=4)
// Round 9: ordinary dispatches; conv (8192 2-chunk units) absorbed as tail
// blocks of the 12 layer dispatches via per-dispatch unit ranges.
// ---------------------------------------------------------------------------

typedef unsigned short u16;
typedef short  short8  __attribute__((ext_vector_type(8)));
typedef unsigned short ushort8 __attribute__((ext_vector_type(8)));
typedef unsigned int   u32x4   __attribute__((ext_vector_type(4)));
typedef float          f32x4   __attribute__((ext_vector_type(4)));

#define DEV static __device__ __forceinline__
#define ARENA 26368
#define CRANGE 683          // conv units per layer dispatch (12*683 >= 8192)

DEV float b2f(u16 u){ union { unsigned int i; float f; } x; x.i = ((unsigned int)u) << 16; return x.f; }
DEV u16  f2b(float f){ union { float f; unsigned int i; } x; x.f = f;
                       unsigned int i = x.i; i += 0x7fffu + ((i >> 16) & 1u); return (u16)(i >> 16); }

DEV float blockSum(float v, float* red, int t){
  #pragma unroll
  for (int m = 32; m; m >>= 1) v += __shfl_xor(v, m, 64);
  __syncthreads();
  if ((t & 63) == 0) red[t >> 6] = v;
  __syncthreads();
  return red[0] + red[1] + red[2] + red[3];
}

struct MP {
  const float *xF, *b_in, *pos, *bq, *bk, *bv, *bo, *lng, *lnb;
  const float *c1w, *c1b, *c2w, *c2b;
  const float *h1w, *h1b, *g1, *be1, *h2w, *h2b, *g2, *be2, *h3w, *h3b;
  const float *srcX, *srcWin, *srcWq, *srcWk, *srcWv, *srcWo;
  float *x1f, *x2sum, *hcat, *sn; int* rctr;
  u16 *x1b, *qkv, *attb, *pwb, *W2r, *cvt;
  const u16 *xc, *Winc, *Wqc, *Wkc, *Wvc, *Woc;
  float* out;
};

// ---------------------------------------------------------------------------
// front: convert 6 tensors to bf16 + sn + W2r + zero x2sum/hcat/rctr
// ---------------------------------------------------------------------------
DEV void front_body(const MP& p, int bid, int t, int G, char* smem){
  long long stride = (long long)G * 256;
  for (long long e = (long long)bid*256 + t; e < 1376256; e += stride){
    const float* s; long long off;
    if (e < 262144){ s = p.srcX;  off = 0; }
    else if (e <  327680){ s = p.srcWin; off = 262144; }
    else if (e <  589824){ s = p.srcWq;  off = 327680; }
    else if (e <  851968){ s = p.srcWk;  off = 589824; }
    else if (e < 1114112){ s = p.srcWv;  off = 851968; }
    else                 { s = p.srcWo;  off = 1114112; }
    p.cvt[e] = f2b(s[e - off]);
  }
  float* red = (float*)smem;
  for (int row = bid; row < 1024; row += G){
    float v = p.xF[row*256 + t];
    float s = blockSum(v*v, red, t);
    if (t == 0) p.sn[row] = s;
    __syncthreads();
  }
  for (int e = bid*256 + t; e < 98304; e += G*256){
    int co = e / 384, kk = e - co*384;
    int k = kk >> 7, ci = kk & 127;
    p.W2r[e] = f2b(p.c2w[co*384 + ci*3 + k]);
  }
  for (int i = bid*256 + t; i < 262144; i += G*256) p.x2sum[i] = 0.f;
  if (bid == 0){
    for (int i = t; i < 1024; i += 256) p.hcat[i] = 0.f;
    if (t < 16) p.rctr[t] = 0;
  }
}

// ---------------------------------------------------------------------------
// 64x64x256 NT GEMM core. arena use: 10240 B
// ---------------------------------------------------------------------------
DEV void gemm64_core(const u16* __restrict__ A, const u16* __restrict__ Bp,
                     int m0, int n0, int t, char* smem, f32x4 acc[4]){
  u16* As = (u16*)smem;            // 64*40
  u16* Bs = (u16*)(smem + 5120);   // 64*40
  int w = t >> 6, lane = t & 63, l15 = lane & 15, quad = lane >> 4;
  for (int k0 = 0; k0 < 256; k0 += 32){
    { int row = t >> 2, c = (t & 3)*8;
      *(u32x4*)&As[row*40 + c] = *(const u32x4*)&A[(m0+row)*256 + k0 + c]; }
    { int krow = t >> 3, nc = t & 7;
      ushort8 v = *(const ushort8*)&Bp[(k0+krow)*256 + n0 + nc*8];
      #pragma unroll
      for (int i = 0; i < 8; i++) Bs[(nc*8 + i)*40 + krow] = v[i]; }
    __syncthreads();
    short8 a = *(const short8*)&As[(w*16 + l15)*40 + quad*8];
    #pragma unroll
    for (int ni = 0; ni < 4; ni++){
      short8 b8 = *(const short8*)&Bs[(ni*16 + l15)*40 + quad*8];
      acc[ni] = __builtin_amdgcn_mfma_f32_16x16x32_bf16(a, b8, acc[ni], 0, 0, 0);
    }
    __syncthreads();
  }
}

// ---------------------------------------------------------------------------
// conv body: unit u in [0,8192): n = u>>3, coHalf = u&1, lq = (u>>1)&3.
// r1t uses XOR-granule swizzle (16B granule slot ^= row&7) to break the
// 8-way bank conflict of the plain stride-136 layout.
// arena: r1t 17952 + pwAll 528 = 18480 B.
// ---------------------------------------------------------------------------
DEV void conv_body(const MP& p, int u, int t, char* smem){
  u16*   r1t   = (u16*)smem;
  float* pwAll = (float*)(smem + 17952);     // 132 floats
  int w = t >> 6, lane = t & 63, l15 = lane & 15, quad = lane >> 4;
  int n = u >> 3, sub = u & 7, co0 = (sub & 1)*128, lq = sub >> 1;
  int lbase = lq*128;

  for (int i = t; i < 132; i += 256){
    int l = lbase - 2 + i;
    pwAll[i] = ((unsigned)l < 512u) ? b2f(p.pwb[n*512 + l]) : 0.f;
  }
  int ci = t & 127, half = t >> 7;
  float w0 = p.c1w[ci*3], w1 = p.c1w[ci*3+1], w2 = p.c1w[ci*3+2], cb = p.c1b[ci];
  int giW = ci >> 3, clW = ci & 7;           // write-side granule decomposition

  short8 aF[12][2];
  #pragma unroll
  for (int s = 0; s < 12; s++)
    #pragma unroll
    for (int mi = 0; mi < 2; mi++)
      aF[s][mi] = *(const short8*)&p.W2r[(co0 + w*32 + mi*16 + l15)*384 + s*32 + quad*8];

  float bias[2][4], accsum[2][4] = {};
  #pragma unroll
  for (int mi = 0; mi < 2; mi++)
    #pragma unroll
    for (int r = 0; r < 4; r++) bias[mi][r] = p.c2b[co0 + w*32 + mi*16 + quad*4 + r];

  for (int cc = 0; cc < 2; cc++){
    int l0 = lbase + cc*64;
    __syncthreads();
    #pragma unroll
    for (int j = 0; j < 33; j++){
      int g = half + 2*j;
      int lidx = l0 - 1 + g;
      int li = cc*64 + g;
      float v = fmaxf(w0*pwAll[li] + w1*pwAll[li+1] + w2*pwAll[li+2] + cb, 0.f);
      v = ((unsigned)lidx < 512u) ? v : 0.f;
      r1t[g*136 + ((giW ^ (g & 7)) << 3) + clW] = f2b(v);
    }
    __syncthreads();
    f32x4 acc[2][4] = {};
    #pragma unroll
    for (int s = 0; s < 12; s++){
      int kq = s >> 2, gi = (s & 3)*4 + quad;
      #pragma unroll
      for (int nj = 0; nj < 4; nj++){
        int g = nj*16 + l15 + kq;
        short8 b8 = *(const short8*)&r1t[g*136 + ((gi ^ (g & 7)) << 3)];
        acc[0][nj] = __builtin_amdgcn_mfma_f32_16x16x32_bf16(aF[s][0], b8, acc[0][nj], 0, 0, 0);
        acc[1][nj] = __builtin_amdgcn_mfma_f32_16x16x32_bf16(aF[s][1], b8, acc[1][nj], 0, 0, 0);
      }
    }
    #pragma unroll
    for (int mi = 0; mi < 2; mi++)
      #pragma unroll
      for (int r = 0; r < 4; r++){
        float s4 = 0.f;
        #pragma unroll
        for (int nj = 0; nj < 4; nj++) s4 += fmaxf(acc[mi][nj][r] + bias[mi][r], 0.f);
        accsum[mi][r] += s4;
      }
  }
  #pragma unroll
  for (int mi = 0; mi < 2; mi++)
    #pragma unroll
    for (int r = 0; r < 4; r++){
      float s = accsum[mi][r];
      s += __shfl_xor(s, 1, 64); s += __shfl_xor(s, 2, 64);
      s += __shfl_xor(s, 4, 64); s += __shfl_xor(s, 8, 64);
      if (l15 == 0)
        atomicAdd(&p.x2sum[n*256 + co0 + w*32 + mi*16 + quad*4 + r], s * (1.f/512.f));
    }
}

// Tail blocks of dispatch d drain units [d*CRANGE, min((d+1)*CRANGE, 8192)).
DEV void conv_tail(const MP& p, int d, int t, char* smem, int* slotS){
  int start = d*CRANGE, end = start + CRANGE;
  if (end > 8192) end = 8192;
  for (;;){
    if (t == 0) *slotS = atomicAdd(&p.rctr[d], 1);
    __syncthreads();
    int u = start + *slotS;
    __syncthreads();
    if (u >= end) break;
    conv_body(p, u, t, smem);
  }
}

// ---------------------------------------------------------------------------
// pw body (unit [0,128)). arena 10240 B
// ---------------------------------------------------------------------------
DEV void pw_body(const MP& p, int u, int t, char* smem){
  u16* As = (u16*)smem;
  u16* Bs = (u16*)(smem + 5120);
  int w = t >> 6, lane = t & 63, l15 = lane & 15, quad = lane >> 4;
  int m0 = (u & 7)*64, n0 = ((u >> 3) & 7)*64, z = u >> 6;
  const u16* A = p.xc + z*131072;
  const float* snp = p.sn + z*512;
  u16* Cb = p.pwb + z*262144;

  f32x4 acc[4] = {};
  for (int k0 = 0; k0 < 256; k0 += 32){
    { int row = t >> 2, c = (t & 3)*8;
      *(u32x4*)&As[row*40 + c] = *(const u32x4*)&A[(m0+row)*256 + k0 + c];
      *(u32x4*)&Bs[row*40 + c] = *(const u32x4*)&A[(n0+row)*256 + k0 + c]; }
    __syncthreads();
    short8 a = *(const short8*)&As[(w*16 + l15)*40 + quad*8];
    #pragma unroll
    for (int ni = 0; ni < 4; ni++){
      short8 b8 = *(const short8*)&Bs[(ni*16 + l15)*40 + quad*8];
      acc[ni] = __builtin_amdgcn_mfma_f32_16x16x32_bf16(a, b8, acc[ni], 0, 0, 0);
    }
    __syncthreads();
  }
  #pragma unroll
  for (int ni = 0; ni < 4; ni++)
    #pragma unroll
    for (int r = 0; r < 4; r++){
      int row = m0 + w*16 + quad*4 + r, col = n0 + ni*16 + l15;
      float dist = fmaxf(snp[row] + snp[col] - 2.f*acc[ni][r], 0.f);
      Cb[row*512 + col] = f2b(__expf(-dist * (1.f/256.f)));
    }
}

DEV void embed_body(const MP& p, int u, int t, char* smem){
  int m0 = (u & 15)*64, n0 = (u >> 4)*64;
  int w = t >> 6, lane = t & 63, l15 = lane & 15, quad = lane >> 4;
  f32x4 acc[4] = {};
  gemm64_core(p.xc, p.Winc, m0, n0, t, smem, acc);
  #pragma unroll
  for (int ni = 0; ni < 4; ni++)
    #pragma unroll
    for (int r = 0; r < 4; r++){
      int row = m0 + w*16 + quad*4 + r, col = n0 + ni*16 + l15;
      float v = acc[ni][r] + p.b_in[col] + p.pos[(row & 511)*256 + col];
      p.x1f[row*256 + col] = v; p.x1b[row*256 + col] = f2b(v);
    }
}

DEV void qkv_body(const MP& p, int L, int u, int t, char* smem){
  int m0 = (u & 15)*64, n0 = ((u >> 4) & 3)*64, z = u >> 6;
  const u16* W = (z == 0) ? (p.Wqc + L*65536) : ((z == 1) ? (p.Wkc + L*65536) : (p.Wvc + L*65536));
  const float* bias = (z == 0) ? (p.bq + L*256) : ((z == 1) ? (p.bk + L*256) : (p.bv + L*256));
  u16* out = p.qkv + z*262144;
  int w = t >> 6, lane = t & 63, l15 = lane & 15, quad = lane >> 4;
  f32x4 acc[4] = {};
  gemm64_core(p.x1b, W, m0, n0, t, smem, acc);
  #pragma unroll
  for (int ni = 0; ni < 4; ni++)
    #pragma unroll
    for (int r = 0; r < 4; r++){
      int row = m0 + w*16 + quad*4 + r, col = n0 + ni*16 + l15;
      out[row*256 + col] = f2b(acc[ni][r] + bias[col]);
    }
}

// ---------------------------------------------------------------------------
// attn body, K chunked (128 keys). arena use max 26112 B. (validated round 8)
// ---------------------------------------------------------------------------
DEV void attn_body(const MP& p, int u, int t, char* smem){
  const u16* Qb = p.qkv;
  const u16* Kb = p.qkv + 262144;
  const u16* Vb = p.qkv + 524288;
  u16* Qs = (u16*)smem;              // 64*32   (QK phase)
  u16* Kc = (u16*)(smem + 4096);     // 128*32  (QK phase)
  u16* Ps = (u16*)smem;              // 64*136  (PV phase, aliases Qs/Kc)
  u16* Vt = (u16*)(smem + 17408);    // 32*136  (PV phase)
  int w = t >> 6, lane = t & 63, l15 = lane & 15, quad = lane >> 4;
  int qt = u & 7, h = (u >> 3) & 7, b = u >> 6;
  int row0 = b*512, colh = h*32;

  { int row = t >> 2, c = (t & 3)*8;
    *(u32x4*)&Qs[row*32 + c] = *(const u32x4*)&Qb[(row0 + qt*64 + row)*256 + colh + c]; }
  __syncthreads();
  short8 aq = *(const short8*)&Qs[(w*16 + l15)*32 + quad*8];

  const f32x4 z4 = {0.f, 0.f, 0.f, 0.f};
  f32x4 sc[32];
  for (int cch = 0; cch < 4; cch++){
    __syncthreads();
    #pragma unroll
    for (int i = 0; i < 2; i++){
      int ci = i*256 + t; int row = ci >> 2, c = (ci & 3)*8;
      *(u32x4*)&Kc[row*32 + c] = *(const u32x4*)&Kb[(row0 + cch*128 + row)*256 + colh + c];
    }
    __syncthreads();
    #pragma unroll
    for (int k2 = 0; k2 < 8; k2++){
      short8 bk8 = *(const short8*)&Kc[(k2*16 + l15)*32 + quad*8];
      sc[cch*8 + k2] = __builtin_amdgcn_mfma_f32_16x16x32_bf16(aq, bk8, z4, 0, 0, 0);
    }
  }
  float mx[4] = {-1e30f, -1e30f, -1e30f, -1e30f};
  #pragma unroll
  for (int kt = 0; kt < 32; kt++)
    #pragma unroll
    for (int r = 0; r < 4; r++) mx[r] = fmaxf(mx[r], sc[kt][r]);
  #pragma unroll
  for (int r = 0; r < 4; r++){
    mx[r] = fmaxf(mx[r], __shfl_xor(mx[r], 1, 64));
    mx[r] = fmaxf(mx[r], __shfl_xor(mx[r], 2, 64));
    mx[r] = fmaxf(mx[r], __shfl_xor(mx[r], 4, 64));
    mx[r] = fmaxf(mx[r], __shfl_xor(mx[r], 8, 64));
  }
  float sm[4] = {0.f, 0.f, 0.f, 0.f};
  const float is = 1.f/16.f;
  #pragma unroll
  for (int kt = 0; kt < 32; kt++)
    #pragma unroll
    for (int r = 0; r < 4; r++){
      float pr = __expf(fminf((sc[kt][r] - mx[r]) * is, 0.f));
      sc[kt][r] = pr; sm[r] += pr;
    }
  #pragma unroll
  for (int r = 0; r < 4; r++){
    sm[r] += __shfl_xor(sm[r], 1, 64); sm[r] += __shfl_xor(sm[r], 2, 64);
    sm[r] += __shfl_xor(sm[r], 4, 64); sm[r] += __shfl_xor(sm[r], 8, 64);
  }
  float inv[4];
  #pragma unroll
  for (int r = 0; r < 4; r++) inv[r] = 1.f / sm[r];

  f32x4 o[2] = {};
  for (int cch = 0; cch < 4; cch++){
    __syncthreads();
    #pragma unroll
    for (int kk = 0; kk < 8; kk++){
      int kt = cch*8 + kk;
      #pragma unroll
      for (int r = 0; r < 4; r++)
        Ps[(w*16 + quad*4 + r)*136 + kk*16 + l15] = f2b(sc[kt][r] * inv[r]);
    }
    #pragma unroll
    for (int i = 0; i < 2; i++){
      int ci = i*256 + t; int key = ci >> 2; int c = (ci & 3)*8;
      ushort8 v = *(const ushort8*)&Vb[(row0 + cch*128 + key)*256 + colh + c];
      #pragma unroll
      for (int j = 0; j < 8; j++) Vt[(c + j)*136 + key] = v[j];
    }
    __syncthreads();
    #pragma unroll
    for (int ks = 0; ks < 4; ks++){
      short8 ap = *(const short8*)&Ps[(w*16 + l15)*136 + ks*32 + quad*8];
      #pragma unroll
      for (int ni = 0; ni < 2; ni++){
        short8 bv = *(const short8*)&Vt[(ni*16 + l15)*136 + ks*32 + quad*8];
        o[ni] = __builtin_amdgcn_mfma_f32_16x16x32_bf16(ap, bv, o[ni], 0, 0, 0);
      }
    }
  }
  #pragma unroll
  for (int ni = 0; ni < 2; ni++)
    #pragma unroll
    for (int r = 0; r < 4; r++)
      p.attb[(row0 + qt*64 + w*16 + quad*4 + r)*256 + colh + ni*16 + l15] = f2b(o[ni][r]);
}

// ---------------------------------------------------------------------------
// projln16: BM=16, BN=256, 64 blocks. GEMM + bias + residual + LN.
// arena: As 1280 + Bs 20480 + red 256 = 22016 B.
// ---------------------------------------------------------------------------
DEV void projln16_body(const MP& p, int L, int u, int t, char* smem){
  const u16* Wo = p.Woc + L*65536;
  const float* bo = p.bo + L*256;
  const float* lng = p.lng + L*256;
  const float* lnb = p.lnb + L*256;
  u16* As = (u16*)smem;                    // 16*40
  u16* Bs = (u16*)(smem + 1280);           // 256*40
  float* red = (float*)(smem + 21760);     // 64 floats
  int w = t >> 6, lane = t & 63, l15 = lane & 15, quad = lane >> 4;
  int m0 = u*16;

  f32x4 acc[4] = {};
  for (int k0 = 0; k0 < 256; k0 += 32){
    if (t < 64){ int row = t >> 2, c = (t & 3)*8;
      *(u32x4*)&As[row*40 + c] = *(const u32x4*)&p.attb[(m0+row)*256 + k0 + c]; }
    #pragma unroll
    for (int it = 0; it < 4; it++){
      int krow = (t >> 5) + it*8, nc = t & 31;
      ushort8 v = *(const ushort8*)&Wo[(k0+krow)*256 + nc*8];
      #pragma unroll
      for (int i = 0; i < 8; i++) Bs[(nc*8 + i)*40 + krow] = v[i];
    }
    __syncthreads();
    short8 a = *(const short8*)&As[l15*40 + quad*8];
    #pragma unroll
    for (int ni = 0; ni < 4; ni++){
      short8 b8 = *(const short8*)&Bs[((w*4 + ni)*16 + l15)*40 + quad*8];
      acc[ni] = __builtin_amdgcn_mfma_f32_16x16x32_bf16(a, b8, acc[ni], 0, 0, 0);
    }
    __syncthreads();
  }
  // epilogue: rows = quad*4+r (16), wave w owns cols w*64 + ni*16 + l15
  float vv[4][4]; float s1[4] = {0.f, 0.f, 0.f, 0.f};
  #pragma unroll
  for (int r = 0; r < 4; r++){
    int row = m0 + quad*4 + r;
    #pragma unroll
    for (int ni = 0; ni < 4; ni++){
      int col = w*64 + ni*16 + l15;
      float v = acc[ni][r] + bo[col] + p.x1f[row*256 + col];
      vv[r][ni] = v; s1[r] += v;
    }
  }
  #pragma unroll
  for (int r = 0; r < 4; r++){
    s1[r] += __shfl_xor(s1[r], 1, 64); s1[r] += __shfl_xor(s1[r], 2, 64);
    s1[r] += __shfl_xor(s1[r], 4, 64); s1[r] += __shfl_xor(s1[r], 8, 64);
    if (l15 == 0) red[w*16 + quad*4 + r] = s1[r];
  }
  __syncthreads();
  float mean[4];
  #pragma unroll
  for (int r = 0; r < 4; r++){
    int row = quad*4 + r;
    mean[r] = (red[row] + red[16 + row] + red[32 + row] + red[48 + row]) * (1.f/256.f);
  }
  __syncthreads();                     // red reuse
  float s2[4] = {0.f, 0.f, 0.f, 0.f};
  #pragma unroll
  for (int r = 0; r < 4; r++)
    #pragma unroll
    for (int ni = 0; ni < 4; ni++){ float d = vv[r][ni] - mean[r]; s2[r] += d*d; }
  #pragma unroll
  for (int r = 0; r < 4; r++){
    s2[r] += __shfl_xor(s2[r], 1, 64); s2[r] += __shfl_xor(s2[r], 2, 64);
    s2[r] += __shfl_xor(s2[r], 4, 64); s2[r] += __shfl_xor(s2[r], 8, 64);
    if (l15 == 0) red[w*16 + quad*4 + r] = s2[r];
  }
  __syncthreads();
  #pragma unroll
  for (int r = 0; r < 4; r++){
    int rowL = quad*4 + r; int row = m0 + rowL;
    float var = (red[rowL] + red[16 + rowL] + red[32 + rowL] + red[48 + rowL]) * (1.f/256.f);
    float rs = rsqrtf(var + 1e-5f);
    #pragma unroll
    for (int ni = 0; ni < 4; ni++){
      int col = w*64 + ni*16 + l15;
      float y = (vv[r][ni] - mean[r]) * rs * lng[col] + lnb[col];
      p.x1f[row*256 + col] = y;
      p.x1b[row*256 + col] = f2b(y);
    }
  }
}

DEV void pool_body(const MP& p, int u, int t){
  int sc = u & 7, b = u >> 3;
  float a1 = 0.f, a2 = 0.f;
  for (int i = 0; i < 64; i++){
    int s = sc*64 + i; int n = b*512 + s;
    a1 += p.x1f[n*256 + t];
    a2 += p.x2sum[n*256 + t] + p.pos[s*256 + t];
  }
  atomicAdd(&p.hcat[b*512 + t], a1);
  atomicAdd(&p.hcat[b*512 + 256 + t], a2);
}

DEV void mlp_body(const MP& p, int b, int t, char* smem){
  float* hv  = (float*)smem;
  float* z1  = (float*)(smem + 2048);
  float* z2  = (float*)(smem + 3072);
  float* red = (float*)(smem + 3584);
  hv[t]       = p.hcat[b*512 + t]       * (1.f/512.f);
  hv[t + 256] = p.hcat[b*512 + 256 + t] * (1.f/512.f);
  __syncthreads();
  float a = p.h1b[t];
  for (int k = 0; k < 512; k++) a += hv[k] * p.h1w[k*256 + t];
  float mean = blockSum(a, red, t) * (1.f/256.f);
  float d = a - mean;
  float var = blockSum(d*d, red, t) * (1.f/256.f);
  float y = d * rsqrtf(var + 1e-5f) * p.g1[t] + p.be1[t];
  z1[t] = fmaxf(y, 0.f);
  __syncthreads();
  float a2 = 0.f;
  if (t < 128){ a2 = p.h2b[t]; for (int k = 0; k < 256; k++) a2 += z1[k] * p.h2w[k*128 + t]; }
  float mean2 = blockSum(t < 128 ? a2 : 0.f, red, t) * (1.f/128.f);
  float d2 = a2 - mean2;
  float var2 = blockSum(t < 128 ? d2*d2 : 0.f, red, t) * (1.f/128.f);
  if (t < 128) z2[t] = fmaxf(d2 * rsqrtf(var2 + 1e-5f) * p.g2[t] + p.be2[t], 0.f);
  __syncthreads();
  float pr = (t < 128) ? z2[t] * p.h3w[t] : 0.f;
  float s = blockSum(pr, red, t);
  if (t == 0) p.out[b] = s + p.h3b[0];
}

// ---------------------------------------------------------------------------
// kernels
// ---------------------------------------------------------------------------
__global__ __launch_bounds__(256) void kF_front(MP p){
  __shared__ __align__(16) char smem[ARENA];
  front_body(p, blockIdx.x, threadIdx.x, gridDim.x, smem);
}
__global__ __launch_bounds__(256) void kF_embedpw(MP p){
  __shared__ __align__(16) char smem[ARENA];
  int bx = blockIdx.x;
  if (bx < 64) embed_body(p, bx, threadIdx.x, smem);
  else pw_body(p, bx - 64, threadIdx.x, smem);
}
__global__ __launch_bounds__(256) void kT_qkv(MP p, int L, int d){
  __shared__ __align__(16) char smem[ARENA];
  __shared__ int slotS;
  int bx = blockIdx.x, t = threadIdx.x;
  if (bx < 192) qkv_body(p, L, bx, t, smem);
  else conv_tail(p, d, t, smem, &slotS);
}
__global__ __launch_bounds__(256) void kT_attn(MP p, int d){
  __shared__ __align__(16) char smem[ARENA];
  __shared__ int slotS;
  int bx = blockIdx.x, t = threadIdx.x;
  if (bx < 128) attn_body(p, bx, t, smem);
  else conv_tail(p, d, t, smem, &slotS);
}
__global__ __launch_bounds__(256) void kT_projln(MP p, int L, int d){
  __shared__ __align__(16) char smem[ARENA];
  __shared__ int slotS;
  int bx = blockIdx.x, t = threadIdx.x;
  if (bx < 64) projln16_body(p, L, bx, t, smem);
  else conv_tail(p, d, t, smem, &slotS);
}
__global__ __launch_bounds__(256) void kF_pool(MP p){
  pool_body(p, blockIdx.x, threadIdx.x);
}
__global__ __launch_bounds__(256) void kF_mlp(MP p){
  __shared__ __align__(16) char smem[ARENA];
  mlp_body(p, blockIdx.x, threadIdx.x, smem);
}

// ---------------------------------------------------------------------------
extern "C" void kernel_launch(void* const* d_in, const int* in_sizes, int n_in,
                              void* d_out, int out_size, void* d_ws, size_t ws_size,
                              hipStream_t stream){
  (void)in_sizes; (void)n_in; (void)out_size; (void)ws_size;
  char* ws = (char*)d_ws;
  MP P;
  P.xF   = (const float*)d_in[0];
  P.b_in = (const float*)d_in[3];
  P.pos  = (const float*)d_in[4];
  P.bq   = (const float*)d_in[9];
  P.bk   = (const float*)d_in[10];
  P.bv   = (const float*)d_in[11];
  P.bo   = (const float*)d_in[12];
  P.lng  = (const float*)d_in[13];
  P.lnb  = (const float*)d_in[14];
  P.c1w  = (const float*)d_in[15];
  P.c1b  = (const float*)d_in[16];
  P.c2w  = (const float*)d_in[17];
  P.c2b  = (const float*)d_in[18];
  P.h1w  = (const float*)d_in[19];
  P.h1b  = (const float*)d_in[20];
  P.g1   = (const float*)d_in[21];
  P.be1  = (const float*)d_in[22];
  P.h2w  = (const float*)d_in[23];
  P.h2b  = (const float*)d_in[24];
  P.g2   = (const float*)d_in[25];
  P.be2  = (const float*)d_in[26];
  P.h3w  = (const float*)d_in[27];
  P.h3b  = (const float*)d_in[28];
  P.srcX  = (const float*)d_in[0];
  P.srcWin= (const float*)d_in[2];
  P.srcWq = (const float*)d_in[5];
  P.srcWk = (const float*)d_in[6];
  P.srcWv = (const float*)d_in[7];
  P.srcWo = (const float*)d_in[8];

  P.x1f   = (float*)(ws + 0);
  P.x2sum = (float*)(ws + 2097152);
  P.hcat  = (float*)(ws + 3145728);
  P.sn    = (float*)(ws + 3149824);
  P.rctr  = (int*)  (ws + 3153920);
  P.x1b   = (u16*)  (ws + 3158016);
  P.qkv   = (u16*)  (ws + 3682304);
  P.attb  = (u16*)  (ws + 5255168);
  P.pwb   = (u16*)  (ws + 5779456);
  P.W2r   = (u16*)  (ws + 6828032);
  P.cvt   = (u16*)  (ws + 8388608);
  P.xc    = P.cvt;
  P.Winc  = P.cvt + 262144;
  P.Wqc   = P.cvt + 327680;
  P.Wkc   = P.cvt + 589824;
  P.Wvc   = P.cvt + 851968;
  P.Woc   = P.cvt + 1114112;
  P.out   = (float*)d_out;

  kF_front  <<<512, 256, 0, stream>>>(P);
  kF_embedpw<<<192, 256, 0, stream>>>(P);
  for (int L = 0; L < 4; L++){
    int d = L*3;
    kT_qkv   <<<192 + 512, 256, 0, stream>>>(P, L, d);
    kT_attn  <<<128 + 512, 256, 0, stream>>>(P, d + 1);
    kT_projln<<<64 + 512, 256, 0, stream>>>(P, L, d + 2);
  }
  kF_pool<<<16, 256, 0, stream>>>(P);
  kF_mlp <<<2, 256, 0, stream>>>(P);
}